// Round 1
// 2476.731 us; speedup vs baseline: 1.9902x; 1.9902x over previous
//
#include <hip/hip_runtime.h>
#include <math.h>

// QuantumMambaSSMCore R8: 4-wave state shard + natural-frame gates.
//  - 256 thr/block (4 waves), 128 blocks; 4 amps (v2) per lane.
//  - Index bits: lane={0,5,1,7,3,9} (as R7), reg={2,6}, wave={4,8}.
//  - Phases A/B identical math to R7 (verified mz masks), output = phased
//    product in frame-0. Then EXPLICIT permutations: P4 = 4 QSVT rings,
//    PL = var CNOT line. Var gates are plain single-qubit gates:
//    8 local (DPP/swizzle/bpermute or register) + 2 cross-wave (LDS, wires 5,1).
//  - Measurement in natural frame: Z_w = sign/selection of T butterfly,
//    X_w = single-bit xdot; final RY fused via cf/sf as R7.
//  - 9 barriers/step; double-buffered 8KB exchange LDS (ex0/ex1).

#define PIF 3.14159265358979323846f

constexpr int NQ = 10, SEQ = 512, NB = 128, NTHR = 256, RECF = 36;

// ---- QSVT phase masks (frame-0), exactly as the verified R7 kernel ----
struct CTbl { int mz[4][NQ]; };
constexpr CTbl build_tbl() {
  CTbl t{};
  unsigned mrow[NQ];
  for (int b = 0; b < NQ; ++b) mrow[b] = 1u << b;
  for (int d = 0; d < 4; ++d) {
    for (int i = 0; i < NQ; ++i) t.mz[d][i] = (int)mrow[9 - i];
    for (int i = 0; i < NQ - 1; ++i) { int bc = 9 - i, bt = 8 - i; mrow[bt] ^= mrow[bc]; }
    mrow[9] ^= mrow[0];
  }
  return t;
}
constexpr CTbl CT = build_tbl();

// ---- index-permutation columns for the CNOT networks (circuit order) ----
// CNOT(c,t) on a basis index: if bit c set, flip bit t.  Columns = image of e_b.
struct PermCols { int c4[10]; int cL[10]; };
constexpr PermCols build_perms() {
  PermCols P{};
  for (int b = 0; b < 10; ++b) {
    int x = 1 << b;
    for (int d = 0; d < 4; ++d) {
      for (int i = 0; i < 9; ++i) { int bc = 9 - i, bt = 8 - i; if ((x >> bc) & 1) x ^= (1 << bt); }
      if (x & 1) x ^= (1 << 9);                       // ring CNOT: bc=0, bt=9
    }
    P.c4[b] = x;
    int y = 1 << b;
    for (int i = 0; i < 9; ++i) { int bc = 9 - i, bt = 8 - i; if ((y >> bc) & 1) y ^= (1 << bt); }
    P.cL[b] = y;
  }
  return P;
}
constexpr PermCols PC = build_perms();

constexpr int lanePart(int x) { return ((x >> 0) & 1) | (((x >> 5) & 1) << 1) |
                                       (((x >> 1) & 1) << 2) | (((x >> 7) & 1) << 3) |
                                       (((x >> 3) & 1) << 4) | (((x >> 9) & 1) << 5); }
constexpr int regPart2(int x)  { return ((x >> 2) & 1) | (((x >> 6) & 1) << 1); }
constexpr int wavePart(int x)  { return ((x >> 4) & 1) | (((x >> 8) & 1) << 1); }

typedef __attribute__((ext_vector_type(2))) float v2;

// ---------------- cross-lane exchange helpers (within one wave) ----------------
template<int C>
__device__ __forceinline__ int dpp1(int x) {
  return __builtin_amdgcn_update_dpp(x, x, C, 0xF, 0xF, false);
}
template<int VL>
__device__ __forceinline__ int lxi(int x) {   // DPP xor-exchange, 1 <= VL <= 15
  if constexpr (VL == 1)  return dpp1<0xB1>(x);
  else if constexpr (VL == 2)  return dpp1<0x4E>(x);
  else if constexpr (VL == 3)  return dpp1<0x1B>(x);
  else if constexpr (VL <= 7) {
    constexpr int q = (VL & 3) ^ 3;
    int y = x;
    if constexpr (q == 1) y = dpp1<0xB1>(y);
    else if constexpr (q == 2) y = dpp1<0x4E>(y);
    else if constexpr (q == 3) y = dpp1<0x1B>(y);
    return dpp1<0x141>(y);                      // ^7
  } else if constexpr (VL >= 12) {
    constexpr int q = (VL & 3) ^ 3;
    int y = x;
    if constexpr (q == 1) y = dpp1<0xB1>(y);
    else if constexpr (q == 2) y = dpp1<0x4E>(y);
    else if constexpr (q == 3) y = dpp1<0x1B>(y);
    return dpp1<0x140>(y);                      // ^15
  } else {
    constexpr int a = VL & 3;
    int y = x;
    if constexpr (a == 1) y = dpp1<0xB1>(y);
    else if constexpr (a == 2) y = dpp1<0x4E>(y);
    else if constexpr (a == 3) y = dpp1<0x1B>(y);
    y = dpp1<0x141>(y);
    return dpp1<0x140>(y);
  }
}
template<int VL>
__device__ __forceinline__ float lx(float x) {
  if constexpr (VL == 0) return x;
  else if constexpr (VL & 32) {
    int addr = (((int)threadIdx.x & 63) ^ VL) << 2;
    return __int_as_float(__builtin_amdgcn_ds_bpermute(addr, __float_as_int(x)));
  } else if constexpr (VL & 16) {
    return __int_as_float(__builtin_amdgcn_ds_swizzle(__float_as_int(x), (VL << 10) | 0x1F));
  } else {
    return __int_as_float(lxi<VL>(__float_as_int(x)));
  }
}
__device__ __forceinline__ float rdl(float x, int l) {
  return __int_as_float(__builtin_amdgcn_readlane(__float_as_int(x), l));
}

// ---------------- SU(2) application ----------------
__device__ __forceinline__ void apply4(v2* amp, const v2* p, bool par, float4 U0, float4 U1) {
  v2 u00 = {U0.x, U0.y}, u01 = {U0.z, U0.w}, u10 = {U1.x, U1.y}, u11 = {U1.z, U1.w};
  v2 A = par ? u11 : u00, B = par ? u10 : u01;
  v2 An = {-A.y, A.y}, Bn = {-B.y, B.y};
#pragma unroll
  for (int r = 0; r < 4; ++r) {
    v2 o = amp[r], q = p[r];
    v2 res = A.x * o;
    res += An * __builtin_shufflevector(o, o, 1, 0);
    res += B.x * q;
    res += Bn * __builtin_shufflevector(q, q, 1, 0);
    amp[r] = res;
  }
}

template<int VL>
__device__ __forceinline__ void gate_lane(v2* amp, float4 U0, float4 U1, int lane) {
  v2 p[4];
#pragma unroll
  for (int r = 0; r < 4; ++r) { p[r].x = lx<VL>(amp[r].x); p[r].y = lx<VL>(amp[r].y); }
  apply4(amp, p, (lane & VL) != 0, U0, U1);
}

template<int VR>
__device__ __forceinline__ void gate_reg(v2* amp, float4 U0, float4 U1) {
  v2 p[4];
#pragma unroll
  for (int r = 0; r < 4; ++r) p[r] = amp[r ^ VR];
  v2 u00 = {U0.x, U0.y}, u01 = {U0.z, U0.w}, u10 = {U1.x, U1.y}, u11 = {U1.z, U1.w};
#pragma unroll
  for (int r = 0; r < 4; ++r) {
    const bool par = (r & VR) != 0;
    v2 A = par ? u11 : u00, B = par ? u10 : u01;
    v2 An = {-A.y, A.y}, Bn = {-B.y, B.y};
    v2 o = amp[r], q = p[r];
    v2 res = A.x * o;
    res += An * __builtin_shufflevector(o, o, 1, 0);
    res += B.x * q;
    res += Bn * __builtin_shufflevector(q, q, 1, 0);
    amp[r] = res;
  }
}

__device__ __forceinline__ void gate_wave(v2* amp, float4 U0, float4 U1,
                                          v2* exb, int wbase, int pbase, bool par) {
#pragma unroll
  for (int r = 0; r < 4; ++r) exb[r * 256 + wbase] = amp[r];
  __syncthreads();
  v2 p[4];
#pragma unroll
  for (int r = 0; r < 4; ++r) p[r] = exb[r * 256 + pbase];
  apply4(amp, p, par, U0, U1);
}

// explicit index permutation: buf[P(idx)] = amp[idx], then linear read-back
__device__ __forceinline__ void permute(v2* amp, v2* buf, int dbase, int o1, int o2, int oidx) {
  buf[dbase]           = amp[0];
  buf[dbase ^ o1]      = amp[1];
  buf[dbase ^ o2]      = amp[2];
  buf[dbase ^ o1 ^ o2] = amp[3];
  __syncthreads();
  amp[0] = buf[oidx];
  amp[1] = buf[oidx | 4];    // phys bit 2
  amp[2] = buf[oidx | 64];   // phys bit 6
  amp[3] = buf[oidx | 68];
}

// ---------------- <X_w>: per-lane partials ----------------
template<int VL>
__device__ __forceinline__ float xdot_lane(const v2* amp) {
  v2 acc = {0.f, 0.f};
#pragma unroll
  for (int r = 0; r < 4; ++r) {
    v2 p; p.x = lx<VL>(amp[r].x); p.y = lx<VL>(amp[r].y);
    acc += amp[r] * p;
  }
  return acc.x + acc.y;
}
template<int VR>
__device__ __forceinline__ float xdot_reg(const v2* amp) {
  v2 acc = {0.f, 0.f};
#pragma unroll
  for (int r = 0; r < 4; ++r) acc += amp[r] * amp[r ^ VR];
  return acc.x + acc.y;
}

// ---------------- main kernel: 4 waves per batch element ----------------
__global__ __launch_bounds__(NTHR, 1) void qmamba_main(
    const float* __restrict__ angles, const float* __restrict__ Wx,
    const float* __restrict__ Wdt, const float* __restrict__ bdt,
    const float* __restrict__ pc, const float* __restrict__ cp,
    float* __restrict__ out)
{
  __shared__ float  tblL[SEQ][RECF];   // 73728 B
  __shared__ float4 uuL[40];           // 640 B
  __shared__ v2     ex0[1024];         // 8192 B exchange buffer A
  __shared__ v2     ex1[1024];         // 8192 B exchange buffer B
  __shared__ float  zb[4][16];         // per-wave z partials

  const int tid  = threadIdx.x;
  const int lane = tid & 63;
  const int wave = tid >> 6;
  const int b    = blockIdx.x;

  // prologue 1: fused variational unitaries U = RZ(g)*RY(be)*RX(al)
  if (tid < 20) {
    int k = tid * 3;
    float al = 0.5f * cp[k], be = 0.5f * cp[k + 1], ga = 0.5f * cp[k + 2];
    float ca = __cosf(al), sa = __sinf(al);
    float cb = __cosf(be), sb = __sinf(be);
    float cg = __cosf(ga), sg = __sinf(ga);
    float2 M00 = make_float2(cb * ca,  sb * sa);
    float2 M01 = make_float2(-sb * ca, -cb * sa);
    float2 M10 = make_float2(sb * ca,  -cb * sa);
    float2 M11 = make_float2(cb * ca,  -sb * sa);
    float2 e0 = make_float2(cg, -sg), e1 = make_float2(cg, sg);
    auto cm = [](float2 a, float2 c) {
      return make_float2(a.x * c.x - a.y * c.y, a.x * c.y + a.y * c.x);
    };
    float2 u00 = cm(M00, e0), u01 = cm(M01, e0), u10 = cm(M10, e1), u11 = cm(M11, e1);
    uuL[2 * tid]     = make_float4(u00.x, u00.y, u01.x, u01.y);
    uuL[2 * tid + 1] = make_float4(u10.x, u10.y, u11.x, u11.y);
  }

  // prologue 2: per-step tables (each thread computes 2 steps)
#pragma unroll 1
  for (int k = 0; k < 2; ++k) {
    const int t = k * NTHR + tid;
    const float* ar = angles + (size_t)(b * SEQ + t) * NQ;
    float a[NQ];
#pragma unroll
    for (int n = 0; n < NQ; ++n) a[n] = ar[n];
    float dtr[5];
#pragma unroll
    for (int r = 0; r < 5; ++r) {
      float acc = 0.f;
#pragma unroll
      for (int n = 0; n < NQ; ++n) acc += a[n] * Wx[r * NQ + n];
      dtr[r] = acc;
    }
    float* rec = &tblL[t][0];
#pragma unroll
    for (int w = 0; w < NQ; ++w) {
      float lin = bdt[w];
#pragma unroll
      for (int r = 0; r < 5; ++r) lin += dtr[r] * Wdt[w * 5 + r];
      float sp = lin > 0.f ? lin + log1pf(__expf(-lin)) : log1pf(__expf(lin));
      float th = tanhf(sp) * PIF;
      float fa = a[w] * th;
      rec[w]      = th;
      rec[12 + w] = __cosf(fa);
      rec[24 + w] = __sinf(fa);
    }
  }
  __syncthreads();

  float pch[4];
#pragma unroll
  for (int d = 0; d < 4; ++d) pch[d] = 0.5f * pc[d] * PIF;

  // Phase-B sign bits: lane parity ^ wave parity of each mz mask
  unsigned PW0 = 0, PW1 = 0;
#pragma unroll
  for (int k = 0; k < 40; ++k) {
    const int m  = CT.mz[k / 10][k % 10];
    const int lm = lanePart(m), wm = wavePart(m);
    unsigned flip = ((unsigned)((__popc(lane & lm) ^ __popc(wave & wm)) & 1)) ^ 1u;
    if (k < 32) PW0 |= flip << k; else PW1 |= flip << (k - 32);
  }

  // permutation bases (image of this thread's lane+wave bits), once per kernel
  int d4 = 0, dL = 0;
  if (lane & 1)  { d4 ^= PC.c4[0]; dL ^= PC.cL[0]; }
  if (lane & 2)  { d4 ^= PC.c4[5]; dL ^= PC.cL[5]; }
  if (lane & 4)  { d4 ^= PC.c4[1]; dL ^= PC.cL[1]; }
  if (lane & 8)  { d4 ^= PC.c4[7]; dL ^= PC.cL[7]; }
  if (lane & 16) { d4 ^= PC.c4[3]; dL ^= PC.cL[3]; }
  if (lane & 32) { d4 ^= PC.c4[9]; dL ^= PC.cL[9]; }
  if (wave & 1)  { d4 ^= PC.c4[4]; dL ^= PC.cL[4]; }
  if (wave & 2)  { d4 ^= PC.c4[8]; dL ^= PC.cL[8]; }

  const int oidx = (lane & 1) | (((lane >> 1) & 1) << 5) | (((lane >> 2) & 1) << 1)
                 | (((lane >> 3) & 1) << 7) | (((lane >> 4) & 1) << 3) | (((lane >> 5) & 1) << 9)
                 | ((wave & 1) << 4) | (((wave >> 1) & 1) << 8);

  const int wbase = wave * 64 + lane;          // own slot in [r][wave][lane] exchange layout
  const int pb1   = (wave ^ 1) * 64 + lane;    // partner across phys bit 4 (wire 5)
  const int pb2   = (wave ^ 2) * 64 + lane;    // partner across phys bit 8 (wire 1)

  float hcw[NQ], hsw[NQ];
#pragma unroll
  for (int w = 0; w < NQ; ++w) { hcw[w] = 1.f; hsw[w] = 0.f; }

  v2 amp[4];

#pragma unroll 1
  for (int t = 0; t < SEQ; ++t) {
    float tha[12];
    {
      const float4* rq = (const float4*)&tblL[t][0];
#pragma unroll
      for (int j = 0; j < 3; ++j) ((float4*)tha)[j] = rq[j];
    }

    // ---- Phase A: real product state from RY(h)|0>
    float F;
    F  = (lane & 1)  ? hsw[9] : hcw[9];
    F *= (lane & 2)  ? hsw[4] : hcw[4];
    F *= (lane & 4)  ? hsw[8] : hcw[8];
    F *= (lane & 8)  ? hsw[2] : hcw[2];
    F *= (lane & 16) ? hsw[6] : hcw[6];
    F *= (lane & 32) ? hsw[0] : hcw[0];
    F *= (wave & 1)  ? hsw[5] : hcw[5];
    F *= (wave & 2)  ? hsw[1] : hcw[1];
    const float G0 = F * hcw[7] * hcw[3];
    const float G1 = F * hsw[7] * hcw[3];
    const float G2 = F * hcw[7] * hsw[3];
    const float G3 = F * hsw[7] * hsw[3];

    // ---- Phase B: fused 40-RZ phase (frame-0)
    float S[4] = {0.f, 0.f, 0.f, 0.f};
#pragma unroll
    for (int k = 0; k < 40; ++k) {
      const int m  = CT.mz[k / 10][k % 10];
      const int gr = regPart2(m);
      float v = pch[k / 10] * tha[k % 10];
      unsigned fl = ((k < 32 ? (PW0 >> k) : (PW1 >> (k - 32))) & 1u) << 31;
      S[gr] += __int_as_float(__float_as_int(v) ^ fl);
    }
    {
      float a0 = S[0], a1 = S[1], a2 = S[2], a3 = S[3];
      float b0 = a0 + a1, b1 = a0 - a1, b2 = a2 + a3, b3 = a2 - a3;
      S[0] = b0 + b2; S[2] = b0 - b2; S[1] = b1 + b3; S[3] = b1 - b3;
    }
    {
      float sn, cs;
      __sincosf(S[0], &sn, &cs); amp[0].x = G0 * cs; amp[0].y = G0 * sn;
      __sincosf(S[1], &sn, &cs); amp[1].x = G1 * cs; amp[1].y = G1 * sn;
      __sincosf(S[2], &sn, &cs); amp[2].x = G2 * cs; amp[2].y = G2 * sn;
      __sincosf(S[3], &sn, &cs); amp[3].x = G3 * cs; amp[3].y = G3 * sn;
    }

    // ---- frame-0 -> natural: accumulated 4-ring permutation
    permute(amp, ex0, d4, PC.c4[2], PC.c4[6], oidx);

    // ---- var layer 0 (plain single-qubit gates, wires 0..9)
    gate_lane<32>(amp, uuL[0],  uuL[1],  lane);                      // w0 (bit9)
    gate_wave    (amp, uuL[2],  uuL[3],  ex1, wbase, pb2, (wave & 2) != 0); // w1 (bit8)
    gate_lane<8> (amp, uuL[4],  uuL[5],  lane);                      // w2 (bit7)
    gate_reg<2>  (amp, uuL[6],  uuL[7]);                             // w3 (bit6)
    gate_lane<2> (amp, uuL[8],  uuL[9],  lane);                      // w4 (bit5)
    gate_wave    (amp, uuL[10], uuL[11], ex0, wbase, pb1, (wave & 1) != 0); // w5 (bit4)
    gate_lane<16>(amp, uuL[12], uuL[13], lane);                      // w6 (bit3)
    gate_reg<1>  (amp, uuL[14], uuL[15]);                            // w7 (bit2)
    gate_lane<4> (amp, uuL[16], uuL[17], lane);                      // w8 (bit1)
    gate_lane<1> (amp, uuL[18], uuL[19], lane);                      // w9 (bit0)

    permute(amp, ex1, dL, PC.cL[2], PC.cL[6], oidx);                 // CNOT line

    // ---- var layer 1
    gate_lane<32>(amp, uuL[20], uuL[21], lane);
    gate_wave    (amp, uuL[22], uuL[23], ex0, wbase, pb2, (wave & 2) != 0);
    gate_lane<8> (amp, uuL[24], uuL[25], lane);
    gate_reg<2>  (amp, uuL[26], uuL[27]);
    gate_lane<2> (amp, uuL[28], uuL[29], lane);
    gate_wave    (amp, uuL[30], uuL[31], ex1, wbase, pb1, (wave & 1) != 0);
    gate_lane<16>(amp, uuL[32], uuL[33], lane);
    gate_reg<1>  (amp, uuL[34], uuL[35]);
    gate_lane<4> (amp, uuL[36], uuL[37], lane);
    gate_lane<1> (amp, uuL[38], uuL[39], lane);

    permute(amp, ex0, dL, PC.cL[2], PC.cL[6], oidx);                 // CNOT line

    // ---- cf/sf tables
    float cfv[12], sfv[12];
    {
      const float4* rq = (const float4*)&tblL[t][0];
#pragma unroll
      for (int j = 0; j < 3; ++j) { ((float4*)cfv)[j] = rq[3 + j]; ((float4*)sfv)[j] = rq[6 + j]; }
    }

    // ---- measurement (natural frame) with fused final RY
    float T[4];
#pragma unroll
    for (int r = 0; r < 4; ++r) T[r] = amp[r].x * amp[r].x + amp[r].y * amp[r].y;
    {
      float a0 = T[0], a1 = T[1], a2 = T[2], a3 = T[3];
      float b0 = a0 + a1, b1 = a0 - a1, b2 = a2 + a3, b3 = a2 - a3;
      T[0] = b0 + b2; T[2] = b0 - b2; T[1] = b1 + b3; T[3] = b1 - b3;
    }

    // shared exchange for the two wave-wire X dots (state is static now)
    v2 pw1[4], pw5[4];
    {
#pragma unroll
      for (int r = 0; r < 4; ++r) ex1[r * 256 + wbase] = amp[r];
      __syncthreads();
#pragma unroll
      for (int r = 0; r < 4; ++r) pw1[r] = ex1[r * 256 + pb2];
#pragma unroll
      for (int r = 0; r < 4; ++r) pw5[r] = ex1[r * 256 + pb1];
    }

    float zv[NQ];
    { float zp = (lane & 32) ? -T[0] : T[0]; zv[0] = cfv[0] * zp - sfv[0] * xdot_lane<32>(amp); }
    { float zp = (wave & 2)  ? -T[0] : T[0];
      v2 acc = {0.f, 0.f};
#pragma unroll
      for (int r = 0; r < 4; ++r) acc += amp[r] * pw1[r];
      zv[1] = cfv[1] * zp - sfv[1] * (acc.x + acc.y); }
    { float zp = (lane & 8)  ? -T[0] : T[0]; zv[2] = cfv[2] * zp - sfv[2] * xdot_lane<8>(amp); }
    { zv[3] = cfv[3] * T[2] - sfv[3] * xdot_reg<2>(amp); }
    { float zp = (lane & 2)  ? -T[0] : T[0]; zv[4] = cfv[4] * zp - sfv[4] * xdot_lane<2>(amp); }
    { float zp = (wave & 1)  ? -T[0] : T[0];
      v2 acc = {0.f, 0.f};
#pragma unroll
      for (int r = 0; r < 4; ++r) acc += amp[r] * pw5[r];
      zv[5] = cfv[5] * zp - sfv[5] * (acc.x + acc.y); }
    { float zp = (lane & 16) ? -T[0] : T[0]; zv[6] = cfv[6] * zp - sfv[6] * xdot_lane<16>(amp); }
    { zv[7] = cfv[7] * T[1] - sfv[7] * xdot_reg<1>(amp); }
    { float zp = (lane & 4)  ? -T[0] : T[0]; zv[8] = cfv[8] * zp - sfv[8] * xdot_lane<4>(amp); }
    { float zp = (lane & 1)  ? -T[0] : T[0]; zv[9] = cfv[9] * zp - sfv[9] * xdot_lane<1>(amp); }

    // per-wave lane reduction: 3 DPP stages + pack + 3 stages -> lane w = partial z_w
#pragma unroll
    for (int w = 0; w < NQ; ++w) {
      zv[w] += lx<1>(zv[w]);
      zv[w] += lx<2>(zv[w]);
      zv[w] += lx<4>(zv[w]);
    }
    const int l7 = lane & 7;
    float c01 = (l7 & 1) ? zv[1] : zv[0];
    float c23 = (l7 & 1) ? zv[3] : zv[2];
    float c45 = (l7 & 1) ? zv[5] : zv[4];
    float c67 = (l7 & 1) ? zv[7] : zv[6];
    float c03 = (l7 & 2) ? c23 : c01;
    float c47 = (l7 & 2) ? c67 : c45;
    float pk  = (l7 & 4) ? c47 : c03;
    pk += lx<8>(pk);  pk += lx<16>(pk);  pk += lx<32>(pk);
    float z8 = zv[8]; z8 += lx<8>(z8); z8 += lx<16>(z8); z8 += lx<32>(z8);
    float z9 = zv[9]; z9 += lx<8>(z9); z9 += lx<16>(z9); z9 += lx<32>(z9);
    float zsel = pk;
    zsel = (lane == 8) ? z8 : zsel;
    zsel = (lane == 9) ? z9 : zsel;

    // cross-wave combine + raw z store + h for next step
    if (lane < NQ) zb[wave][lane] = zsel;
    __syncthreads();
    float z = 0.f;
    if (lane < NQ) {
      z = zb[0][lane] + zb[1][lane] + zb[2][lane] + zb[3][lane];
      if (wave == 0) out[(size_t)(b * SEQ + t) * NQ + lane] = z;
    }
    float sn_h, cs_h;
    __sincosf(0.5f * z, &sn_h, &cs_h);
#pragma unroll
    for (int w = 0; w < NQ; ++w) { hcw[w] = rdl(cs_h, w); hsw[w] = rdl(sn_h, w); }
  }
}

// ---------------- post kernel: out = C*z + D*a, in place ----------------
__global__ __launch_bounds__(256) void qmamba_post(
    const float* __restrict__ angles, const float* __restrict__ Wx,
    const float* __restrict__ Dg, float* __restrict__ out)
{
  int i = blockIdx.x * 256 + threadIdx.x;          // 0 .. 128*512*10-1
  if (i >= NB * SEQ * NQ) return;
  int w  = i % NQ;
  int bt = i / NQ;
  const float* a = angles + (size_t)bt * NQ;
  float C = 0.f;
#pragma unroll
  for (int n = 0; n < NQ; ++n) C += a[n] * Wx[(15 + w) * NQ + n];
  float z = out[i];
  out[i] = C * z + Dg[w] * a[w];
}

extern "C" void kernel_launch(void* const* d_in, const int* in_sizes, int n_in,
                              void* d_out, int out_size, void* d_ws, size_t ws_size,
                              hipStream_t stream) {
  (void)in_sizes; (void)n_in; (void)out_size; (void)d_ws; (void)ws_size;
  const float* angles = (const float*)d_in[0];
  const float* Wx     = (const float*)d_in[1];
  const float* Wdt    = (const float*)d_in[2];
  const float* bdt    = (const float*)d_in[3];
  const float* pc     = (const float*)d_in[4];
  const float* cp     = (const float*)d_in[5];
  const float* Dg     = (const float*)d_in[6];
  float* out = (float*)d_out;
  hipLaunchKernelGGL(qmamba_main, dim3(NB), dim3(NTHR), 0, stream,
                     angles, Wx, Wdt, bdt, pc, cp, out);
  hipLaunchKernelGGL(qmamba_post, dim3((NB * SEQ * NQ + 255) / 256), dim3(256), 0, stream,
                     angles, Wx, Dg, out);
}

// Round 2
// 2221.052 us; speedup vs baseline: 2.2193x; 1.1151x over previous
//
#include <hip/hip_runtime.h>
#include <math.h>

// QuantumMambaSSMCore R9: 8-wave shard (512 thr), 2 amps/thread, 4 barriers/step.
//  - Index bits: lane={0,5,1,7,3,9} (wires 9,4,8,2,6,0), reg={2} (wire 7),
//    wave={4,8,6} (wires 5,1,3).
//  - Each permutation (P4, PL, PL) is merged with the following cross-wave
//    work: scatter-write permuted state -> barrier -> read 8 wave-subspace
//    values -> flat 8-coeff complex sum applies all 3 wave-wire gates of the
//    layer (coeffs constant, precomputed). Final PL merges with measurement
//    (partner reads from the permuted buffer). 4 barriers/step total.
//  - Bank swizzle swz(j)=j^((j>>5&1)<<2)^((j>>7)&1): linear reads land
//    4 lanes/bank-pair (minimal for ds_read_b64).

#define PIF 3.14159265358979323846f

constexpr int NQ = 10, SEQ = 512, NB = 128, NTHR = 512, RECF = 36;

// ---- QSVT phase masks (frame-0), verified in R7/R8 ----
struct CTbl { int mz[4][NQ]; };
constexpr CTbl build_tbl() {
  CTbl t{};
  unsigned mrow[NQ];
  for (int b = 0; b < NQ; ++b) mrow[b] = 1u << b;
  for (int d = 0; d < 4; ++d) {
    for (int i = 0; i < NQ; ++i) t.mz[d][i] = (int)mrow[9 - i];
    for (int i = 0; i < NQ - 1; ++i) { int bc = 9 - i, bt = 8 - i; mrow[bt] ^= mrow[bc]; }
    mrow[9] ^= mrow[0];
  }
  return t;
}
constexpr CTbl CT = build_tbl();

// ---- index-permutation columns for the CNOT networks (circuit order) ----
struct PermCols { int c4[10]; int cL[10]; };
constexpr PermCols build_perms() {
  PermCols P{};
  for (int b = 0; b < 10; ++b) {
    int x = 1 << b;
    for (int d = 0; d < 4; ++d) {
      for (int i = 0; i < 9; ++i) { int bc = 9 - i, bt = 8 - i; if ((x >> bc) & 1) x ^= (1 << bt); }
      if (x & 1) x ^= (1 << 9);                       // ring CNOT: bc=0, bt=9
    }
    P.c4[b] = x;
    int y = 1 << b;
    for (int i = 0; i < 9; ++i) { int bc = 9 - i, bt = 8 - i; if ((y >> bc) & 1) y ^= (1 << bt); }
    P.cL[b] = y;
  }
  return P;
}
constexpr PermCols PC = build_perms();

constexpr int lanePart(int x)  { return ((x >> 0) & 1) | (((x >> 5) & 1) << 1) |
                                        (((x >> 1) & 1) << 2) | (((x >> 7) & 1) << 3) |
                                        (((x >> 3) & 1) << 4) | (((x >> 9) & 1) << 5); }
constexpr int wavePart8(int x) { return ((x >> 4) & 1) | (((x >> 8) & 1) << 1) |
                                        (((x >> 6) & 1) << 2); }

typedef __attribute__((ext_vector_type(2))) float v2;

// wave-gate partner offsets: v bit0->phys4, bit1->phys8, bit2->phys6
constexpr int VOFS[8] = {0, 16, 256, 272, 64, 80, 320, 336};

// ---------------- cross-lane exchange helpers (within one wave) ----------------
template<int C>
__device__ __forceinline__ int dpp1(int x) {
  return __builtin_amdgcn_update_dpp(x, x, C, 0xF, 0xF, false);
}
template<int VL>
__device__ __forceinline__ int lxi(int x) {   // DPP xor-exchange, 1 <= VL <= 15
  if constexpr (VL == 1)  return dpp1<0xB1>(x);
  else if constexpr (VL == 2)  return dpp1<0x4E>(x);
  else if constexpr (VL == 3)  return dpp1<0x1B>(x);
  else if constexpr (VL <= 7) {
    constexpr int q = (VL & 3) ^ 3;
    int y = x;
    if constexpr (q == 1) y = dpp1<0xB1>(y);
    else if constexpr (q == 2) y = dpp1<0x4E>(y);
    else if constexpr (q == 3) y = dpp1<0x1B>(y);
    return dpp1<0x141>(y);                      // ^7
  } else if constexpr (VL >= 12) {
    constexpr int q = (VL & 3) ^ 3;
    int y = x;
    if constexpr (q == 1) y = dpp1<0xB1>(y);
    else if constexpr (q == 2) y = dpp1<0x4E>(y);
    else if constexpr (q == 3) y = dpp1<0x1B>(y);
    return dpp1<0x140>(y);                      // ^15
  } else {
    constexpr int a = VL & 3;
    int y = x;
    if constexpr (a == 1) y = dpp1<0xB1>(y);
    else if constexpr (a == 2) y = dpp1<0x4E>(y);
    else if constexpr (a == 3) y = dpp1<0x1B>(y);
    y = dpp1<0x141>(y);
    return dpp1<0x140>(y);
  }
}
template<int VL>
__device__ __forceinline__ float lx(float x) {
  if constexpr (VL == 0) return x;
  else if constexpr (VL & 32) {
    int addr = (((int)threadIdx.x & 63) ^ VL) << 2;
    return __int_as_float(__builtin_amdgcn_ds_bpermute(addr, __float_as_int(x)));
  } else if constexpr (VL & 16) {
    return __int_as_float(__builtin_amdgcn_ds_swizzle(__float_as_int(x), (VL << 10) | 0x1F));
  } else {
    return __int_as_float(lxi<VL>(__float_as_int(x)));
  }
}
__device__ __forceinline__ float rdl(float x, int l) {
  return __int_as_float(__builtin_amdgcn_readlane(__float_as_int(x), l));
}

// ---- LDS bank swizzle for the 1024-entry v2 exchange buffers ----
__device__ __forceinline__ int swz(int j) {
  return j ^ (((j >> 5) & 1) << 2) ^ ((j >> 7) & 1);
}

// ---------------- SU(2) application over 2 regs ----------------
__device__ __forceinline__ void apply2(v2* amp, const v2* p, bool par, float4 U0, float4 U1) {
  v2 u00 = {U0.x, U0.y}, u01 = {U0.z, U0.w}, u10 = {U1.x, U1.y}, u11 = {U1.z, U1.w};
  v2 A = par ? u11 : u00, B = par ? u10 : u01;
  v2 An = {-A.y, A.y}, Bn = {-B.y, B.y};
#pragma unroll
  for (int r = 0; r < 2; ++r) {
    v2 o = amp[r], q = p[r];
    v2 res = A.x * o;
    res += An * __builtin_shufflevector(o, o, 1, 0);
    res += B.x * q;
    res += Bn * __builtin_shufflevector(q, q, 1, 0);
    amp[r] = res;
  }
}

template<int VL>
__device__ __forceinline__ void gate_lane2(v2* amp, float4 U0, float4 U1, int lane) {
  v2 p[2];
#pragma unroll
  for (int r = 0; r < 2; ++r) { p[r].x = lx<VL>(amp[r].x); p[r].y = lx<VL>(amp[r].y); }
  apply2(amp, p, (lane & VL) != 0, U0, U1);
}

__device__ __forceinline__ void gate_reg1(v2* amp, float4 U0, float4 U1) {
  v2 u00 = {U0.x, U0.y}, u01 = {U0.z, U0.w}, u10 = {U1.x, U1.y}, u11 = {U1.z, U1.w};
  v2 o0 = amp[0], o1 = amp[1];
  v2 a0 = {0.f, 0.f}, a1 = {0.f, 0.f};
  a0.x += u00.x * o0.x - u00.y * o0.y;  a0.y += u00.x * o0.y + u00.y * o0.x;
  a0.x += u01.x * o1.x - u01.y * o1.y;  a0.y += u01.x * o1.y + u01.y * o1.x;
  a1.x += u10.x * o0.x - u10.y * o0.y;  a1.y += u10.x * o0.y + u10.y * o0.x;
  a1.x += u11.x * o1.x - u11.y * o1.y;  a1.y += u11.x * o1.y + u11.y * o1.x;
  amp[0] = a0; amp[1] = a1;
}

// ---------------- <X_w>: per-lane partials ----------------
template<int VL>
__device__ __forceinline__ float xdot_lane2(const v2* amp) {
  v2 acc = {0.f, 0.f};
#pragma unroll
  for (int r = 0; r < 2; ++r) {
    v2 p; p.x = lx<VL>(amp[r].x); p.y = lx<VL>(amp[r].y);
    acc += amp[r] * p;
  }
  return acc.x + acc.y;
}

// ---------------- main kernel: 8 waves per batch element ----------------
__global__ __launch_bounds__(NTHR, 2) void qmamba_main(
    const float* __restrict__ angles, const float* __restrict__ Wx,
    const float* __restrict__ Wdt, const float* __restrict__ bdt,
    const float* __restrict__ pc, const float* __restrict__ cp,
    float* __restrict__ out)
{
  __shared__ float  tblL[SEQ][RECF];   // 73728 B
  __shared__ float4 uuL[40];           // 640 B
  __shared__ v2     ex0[1024];         // 8192 B
  __shared__ v2     ex1[1024];         // 8192 B
  __shared__ float  zb[8][16];         // 512 B

  const int tid  = threadIdx.x;
  const int lane = tid & 63;
  const int wave = tid >> 6;
  const int b    = blockIdx.x;

  // prologue 1: fused variational unitaries U = RZ(g)*RY(be)*RX(al)
  if (tid < 20) {
    int k = tid * 3;
    float al = 0.5f * cp[k], be = 0.5f * cp[k + 1], ga = 0.5f * cp[k + 2];
    float ca = __cosf(al), sa = __sinf(al);
    float cb = __cosf(be), sb = __sinf(be);
    float cg = __cosf(ga), sg = __sinf(ga);
    float2 M00 = make_float2(cb * ca,  sb * sa);
    float2 M01 = make_float2(-sb * ca, -cb * sa);
    float2 M10 = make_float2(sb * ca,  -cb * sa);
    float2 M11 = make_float2(cb * ca,  -sb * sa);
    float2 e0 = make_float2(cg, -sg), e1 = make_float2(cg, sg);
    auto cm = [](float2 a, float2 c) {
      return make_float2(a.x * c.x - a.y * c.y, a.x * c.y + a.y * c.x);
    };
    float2 u00 = cm(M00, e0), u01 = cm(M01, e0), u10 = cm(M10, e1), u11 = cm(M11, e1);
    uuL[2 * tid]     = make_float4(u00.x, u00.y, u01.x, u01.y);
    uuL[2 * tid + 1] = make_float4(u10.x, u10.y, u11.x, u11.y);
  }

  // prologue 2: per-step tables (each thread computes exactly one step)
  {
    const int t = tid;
    const float* ar = angles + (size_t)(b * SEQ + t) * NQ;
    float a[NQ];
#pragma unroll
    for (int n = 0; n < NQ; ++n) a[n] = ar[n];
    float dtr[5];
#pragma unroll
    for (int r = 0; r < 5; ++r) {
      float acc = 0.f;
#pragma unroll
      for (int n = 0; n < NQ; ++n) acc += a[n] * Wx[r * NQ + n];
      dtr[r] = acc;
    }
    float* rec = &tblL[t][0];
#pragma unroll
    for (int w = 0; w < NQ; ++w) {
      float lin = bdt[w];
#pragma unroll
      for (int r = 0; r < 5; ++r) lin += dtr[r] * Wdt[w * 5 + r];
      float sp = lin > 0.f ? lin + log1pf(__expf(-lin)) : log1pf(__expf(lin));
      float th = tanhf(sp) * PIF;
      float fa = a[w] * th;
      rec[w]      = th;
      rec[12 + w] = __cosf(fa);
      rec[24 + w] = __sinf(fa);
    }
  }
  __syncthreads();

  float pch[4];
#pragma unroll
  for (int d = 0; d < 4; ++d) pch[d] = 0.5f * pc[d] * PIF;

  // wave-gate flat-sum coefficients (constants; wires 5,1,3 <-> wave bits 0,1,2)
  v2 cw0[8], cw1[8];
  {
    const int s5 = wave & 1, s1 = (wave >> 1) & 1, s3 = (wave >> 2) & 1;
    auto ent = [&](int g, int row, int col) -> v2 {
      float4 R = uuL[2 * g + row];
      return col ? v2{R.z, R.w} : v2{R.x, R.y};
    };
    auto cmul = [](v2 a, v2 c) -> v2 {
      return v2{a.x * c.x - a.y * c.y, a.x * c.y + a.y * c.x};
    };
#pragma unroll
    for (int v = 0; v < 8; ++v) {
      const int v5 = v & 1, v1 = (v >> 1) & 1, v3 = (v >> 2) & 1;
      cw0[v] = cmul(cmul(ent(5,  s5, s5 ^ v5), ent(1,  s1, s1 ^ v1)), ent(3,  s3, s3 ^ v3));
      cw1[v] = cmul(cmul(ent(15, s5, s5 ^ v5), ent(11, s1, s1 ^ v1)), ent(13, s3, s3 ^ v3));
    }
  }

  // Phase-B sign bits: (lane parity ^ wave parity) of each mz mask
  unsigned PW0 = 0, PW1 = 0;
#pragma unroll
  for (int k = 0; k < 40; ++k) {
    const int m  = CT.mz[k / 10][k % 10];
    const int lm = lanePart(m), wm = wavePart8(m);
    unsigned flip = ((unsigned)((__popc(lane & lm) ^ __popc(wave & wm)) & 1)) ^ 1u;
    if (k < 32) PW0 |= flip << k; else PW1 |= flip << (k - 32);
  }

  // permutation write bases (image of this thread's lane+wave bits)
  int d4 = 0, dL = 0;
  if (lane & 1)  { d4 ^= PC.c4[0]; dL ^= PC.cL[0]; }
  if (lane & 2)  { d4 ^= PC.c4[5]; dL ^= PC.cL[5]; }
  if (lane & 4)  { d4 ^= PC.c4[1]; dL ^= PC.cL[1]; }
  if (lane & 8)  { d4 ^= PC.c4[7]; dL ^= PC.cL[7]; }
  if (lane & 16) { d4 ^= PC.c4[3]; dL ^= PC.cL[3]; }
  if (lane & 32) { d4 ^= PC.c4[9]; dL ^= PC.cL[9]; }
  if (wave & 1)  { d4 ^= PC.c4[4]; dL ^= PC.cL[4]; }
  if (wave & 2)  { d4 ^= PC.c4[8]; dL ^= PC.cL[8]; }
  if (wave & 4)  { d4 ^= PC.c4[6]; dL ^= PC.cL[6]; }
  const int oR4 = PC.c4[2], oRL = PC.cL[2];

  const int oidx = (lane & 1) | (((lane >> 1) & 1) << 5) | (((lane >> 2) & 1) << 1)
                 | (((lane >> 3) & 1) << 7) | (((lane >> 4) & 1) << 3) | (((lane >> 5) & 1) << 9)
                 | ((wave & 1) << 4) | (((wave >> 1) & 1) << 8) | (((wave >> 2) & 1) << 6);

  float hcw[NQ], hsw[NQ];
#pragma unroll
  for (int w = 0; w < NQ; ++w) { hcw[w] = 1.f; hsw[w] = 0.f; }

  v2 amp[2];

#pragma unroll 1
  for (int t = 0; t < SEQ; ++t) {
    float tha[12];
    {
      const float4* rq = (const float4*)&tblL[t][0];
#pragma unroll
      for (int j = 0; j < 3; ++j) ((float4*)tha)[j] = rq[j];
    }

    // ---- Phase A: real product state from RY(h)|0>
    float F;
    F  = (lane & 1)  ? hsw[9] : hcw[9];
    F *= (lane & 2)  ? hsw[4] : hcw[4];
    F *= (lane & 4)  ? hsw[8] : hcw[8];
    F *= (lane & 8)  ? hsw[2] : hcw[2];
    F *= (lane & 16) ? hsw[6] : hcw[6];
    F *= (lane & 32) ? hsw[0] : hcw[0];
    F *= (wave & 1)  ? hsw[5] : hcw[5];
    F *= (wave & 2)  ? hsw[1] : hcw[1];
    F *= (wave & 4)  ? hsw[3] : hcw[3];
    const float G0 = F * hcw[7];
    const float G1 = F * hsw[7];

    // ---- Phase B: fused 40-RZ phase (frame-0), reg dim = 1 bit
    float S0 = 0.f, S1 = 0.f;
#pragma unroll
    for (int k = 0; k < 40; ++k) {
      const int m  = CT.mz[k / 10][k % 10];
      float v = pch[k / 10] * tha[k % 10];
      unsigned fl = ((k < 32 ? (PW0 >> k) : (PW1 >> (k - 32))) & 1u) << 31;
      float sv = __int_as_float(__float_as_int(v) ^ fl);
      if ((m >> 2) & 1) S1 += sv; else S0 += sv;
    }
    {
      float sn, cs;
      __sincosf(S0 + S1, &sn, &cs); amp[0].x = G0 * cs; amp[0].y = G0 * sn;
      __sincosf(S0 - S1, &sn, &cs); amp[1].x = G1 * cs; amp[1].y = G1 * sn;
    }

    // ---- P4 permute merged with layer-0 wave gates ----
    ex0[swz(d4)]       = amp[0];
    ex0[swz(d4 ^ oR4)] = amp[1];
    __syncthreads();
    {
      v2 pv0[8], pv1[8];
#pragma unroll
      for (int v = 0; v < 8; ++v) {
        const int base = oidx ^ VOFS[v];
        pv0[v] = ex0[swz(base)];
        pv1[v] = ex0[swz(base | 4)];
      }
      v2 a0 = {0.f, 0.f}, a1 = {0.f, 0.f};
#pragma unroll
      for (int v = 0; v < 8; ++v) {
        v2 c = cw0[v];
        a0.x += c.x * pv0[v].x - c.y * pv0[v].y;
        a0.y += c.x * pv0[v].y + c.y * pv0[v].x;
        a1.x += c.x * pv1[v].x - c.y * pv1[v].y;
        a1.y += c.x * pv1[v].y + c.y * pv1[v].x;
      }
      amp[0] = a0; amp[1] = a1;
    }
    // layer-0 local gates (wires 0,2,4,6,7,8,9)
    gate_lane2<32>(amp, uuL[0],  uuL[1],  lane);
    gate_lane2<8> (amp, uuL[4],  uuL[5],  lane);
    gate_lane2<2> (amp, uuL[8],  uuL[9],  lane);
    gate_lane2<16>(amp, uuL[12], uuL[13], lane);
    gate_reg1     (amp, uuL[14], uuL[15]);
    gate_lane2<4> (amp, uuL[16], uuL[17], lane);
    gate_lane2<1> (amp, uuL[18], uuL[19], lane);

    // ---- PL permute merged with layer-1 wave gates ----
    ex1[swz(dL)]       = amp[0];
    ex1[swz(dL ^ oRL)] = amp[1];
    __syncthreads();
    {
      v2 pv0[8], pv1[8];
#pragma unroll
      for (int v = 0; v < 8; ++v) {
        const int base = oidx ^ VOFS[v];
        pv0[v] = ex1[swz(base)];
        pv1[v] = ex1[swz(base | 4)];
      }
      v2 a0 = {0.f, 0.f}, a1 = {0.f, 0.f};
#pragma unroll
      for (int v = 0; v < 8; ++v) {
        v2 c = cw1[v];
        a0.x += c.x * pv0[v].x - c.y * pv0[v].y;
        a0.y += c.x * pv0[v].y + c.y * pv0[v].x;
        a1.x += c.x * pv1[v].x - c.y * pv1[v].y;
        a1.y += c.x * pv1[v].y + c.y * pv1[v].x;
      }
      amp[0] = a0; amp[1] = a1;
    }
    // layer-1 local gates
    gate_lane2<32>(amp, uuL[20], uuL[21], lane);
    gate_lane2<8> (amp, uuL[24], uuL[25], lane);
    gate_lane2<2> (amp, uuL[28], uuL[29], lane);
    gate_lane2<16>(amp, uuL[32], uuL[33], lane);
    gate_reg1     (amp, uuL[34], uuL[35]);
    gate_lane2<4> (amp, uuL[36], uuL[37], lane);
    gate_lane2<1> (amp, uuL[38], uuL[39], lane);

    // ---- final PL permute merged with measurement ----
    ex0[swz(dL)]       = amp[0];
    ex0[swz(dL ^ oRL)] = amp[1];
    __syncthreads();
    v2 pw5[2], pw1[2], pw3[2];
    amp[0] = ex0[swz(oidx)];
    amp[1] = ex0[swz(oidx | 4)];
    pw5[0] = ex0[swz(oidx ^ 16)];   pw5[1] = ex0[swz((oidx ^ 16) | 4)];
    pw1[0] = ex0[swz(oidx ^ 256)];  pw1[1] = ex0[swz((oidx ^ 256) | 4)];
    pw3[0] = ex0[swz(oidx ^ 64)];   pw3[1] = ex0[swz((oidx ^ 64) | 4)];

    float cfv[12], sfv[12];
    {
      const float4* rq = (const float4*)&tblL[t][0];
#pragma unroll
      for (int j = 0; j < 3; ++j) { ((float4*)cfv)[j] = rq[3 + j]; ((float4*)sfv)[j] = rq[6 + j]; }
    }

    const float n0 = amp[0].x * amp[0].x + amp[0].y * amp[0].y;
    const float n1 = amp[1].x * amp[1].x + amp[1].y * amp[1].y;
    const float T0 = n0 + n1;
    const float T1 = n0 - n1;

    auto vdot2 = [](const v2* a, const v2* p) {
      v2 acc = a[0] * p[0] + a[1] * p[1];
      return acc.x + acc.y;
    };

    float zv[NQ];
    { float zp = (lane & 32) ? -T0 : T0; zv[0] = cfv[0] * zp - sfv[0] * xdot_lane2<32>(amp); }
    { float zp = (wave & 2)  ? -T0 : T0; zv[1] = cfv[1] * zp - sfv[1] * vdot2(amp, pw1); }
    { float zp = (lane & 8)  ? -T0 : T0; zv[2] = cfv[2] * zp - sfv[2] * xdot_lane2<8>(amp); }
    { float zp = (wave & 4)  ? -T0 : T0; zv[3] = cfv[3] * zp - sfv[3] * vdot2(amp, pw3); }
    { float zp = (lane & 2)  ? -T0 : T0; zv[4] = cfv[4] * zp - sfv[4] * xdot_lane2<2>(amp); }
    { float zp = (wave & 1)  ? -T0 : T0; zv[5] = cfv[5] * zp - sfv[5] * vdot2(amp, pw5); }
    { float zp = (lane & 16) ? -T0 : T0; zv[6] = cfv[6] * zp - sfv[6] * xdot_lane2<16>(amp); }
    { float xr = 2.f * (amp[0].x * amp[1].x + amp[0].y * amp[1].y);
      zv[7] = cfv[7] * T1 - sfv[7] * xr; }
    { float zp = (lane & 4)  ? -T0 : T0; zv[8] = cfv[8] * zp - sfv[8] * xdot_lane2<4>(amp); }
    { float zp = (lane & 1)  ? -T0 : T0; zv[9] = cfv[9] * zp - sfv[9] * xdot_lane2<1>(amp); }

    // per-wave lane reduction: 3 DPP stages + pack + 3 stages -> lane w = partial z_w
#pragma unroll
    for (int w = 0; w < NQ; ++w) {
      zv[w] += lx<1>(zv[w]);
      zv[w] += lx<2>(zv[w]);
      zv[w] += lx<4>(zv[w]);
    }
    const int l7 = lane & 7;
    float c01 = (l7 & 1) ? zv[1] : zv[0];
    float c23 = (l7 & 1) ? zv[3] : zv[2];
    float c45 = (l7 & 1) ? zv[5] : zv[4];
    float c67 = (l7 & 1) ? zv[7] : zv[6];
    float c03 = (l7 & 2) ? c23 : c01;
    float c47 = (l7 & 2) ? c67 : c45;
    float pk  = (l7 & 4) ? c47 : c03;
    pk += lx<8>(pk);  pk += lx<16>(pk);  pk += lx<32>(pk);
    float z8 = zv[8]; z8 += lx<8>(z8); z8 += lx<16>(z8); z8 += lx<32>(z8);
    float z9 = zv[9]; z9 += lx<8>(z9); z9 += lx<16>(z9); z9 += lx<32>(z9);
    float zsel = pk;
    zsel = (lane == 8) ? z8 : zsel;
    zsel = (lane == 9) ? z9 : zsel;

    // cross-wave combine + raw z store + h for next step
    if (lane < NQ) zb[wave][lane] = zsel;
    __syncthreads();
    float z = 0.f;
    if (lane < NQ) {
      z = zb[0][lane] + zb[1][lane] + zb[2][lane] + zb[3][lane]
        + zb[4][lane] + zb[5][lane] + zb[6][lane] + zb[7][lane];
      if (wave == 0) out[(size_t)(b * SEQ + t) * NQ + lane] = z;
    }
    float sn_h, cs_h;
    __sincosf(0.5f * z, &sn_h, &cs_h);
#pragma unroll
    for (int w = 0; w < NQ; ++w) { hcw[w] = rdl(cs_h, w); hsw[w] = rdl(sn_h, w); }
  }
}

// ---------------- post kernel: out = C*z + D*a, in place ----------------
__global__ __launch_bounds__(256) void qmamba_post(
    const float* __restrict__ angles, const float* __restrict__ Wx,
    const float* __restrict__ Dg, float* __restrict__ out)
{
  int i = blockIdx.x * 256 + threadIdx.x;          // 0 .. 128*512*10-1
  if (i >= NB * SEQ * NQ) return;
  int w  = i % NQ;
  int bt = i / NQ;
  const float* a = angles + (size_t)bt * NQ;
  float C = 0.f;
#pragma unroll
  for (int n = 0; n < NQ; ++n) C += a[n] * Wx[(15 + w) * NQ + n];
  float z = out[i];
  out[i] = C * z + Dg[w] * a[w];
}

extern "C" void kernel_launch(void* const* d_in, const int* in_sizes, int n_in,
                              void* d_out, int out_size, void* d_ws, size_t ws_size,
                              hipStream_t stream) {
  (void)in_sizes; (void)n_in; (void)out_size; (void)d_ws; (void)ws_size;
  const float* angles = (const float*)d_in[0];
  const float* Wx     = (const float*)d_in[1];
  const float* Wdt    = (const float*)d_in[2];
  const float* bdt    = (const float*)d_in[3];
  const float* pc     = (const float*)d_in[4];
  const float* cp     = (const float*)d_in[5];
  const float* Dg     = (const float*)d_in[6];
  float* out = (float*)d_out;
  hipLaunchKernelGGL(qmamba_main, dim3(NB), dim3(NTHR), 0, stream,
                     angles, Wx, Wdt, bdt, pc, cp, out);
  hipLaunchKernelGGL(qmamba_post, dim3((NB * SEQ * NQ + 255) / 256), dim3(256), 0, stream,
                     angles, Wx, Dg, out);
}